// Round 8
// baseline (264.354 us; speedup 1.0000x reference)
//
#include <hip/hip_runtime.h>

// CBC (classification-by-components) fused kernel, v7 — thread-per-row-slice.
// x:[B,1024] f32, components:[5,1024] f32, reasonings:[5,3,2] f32 -> probs:[B,3] f32.
//
// History: v1 wave-per-row 35us / v4 LDS 39 / v5 prefetch 47 / v6 pingpong 44.
// All wave-per-row variants sit at ~3.7 TB/s: the {64-lane load burst ->
// compute -> 30-shuffle butterfly -> store} phase structure is the latency
// wall. v7 deletes the phases: each thread owns a 128-col slice of one row
// (8 threads/row) and streams {1 global f4 + 5 LDS comp f4 + 40 VALU} x 32
// iterations with no synchronization points. Reduction is 15 shuffles over
// 3 steps (8-lane groups). Comps in LDS, conflict-free via index rotation:
// ri=(i+q)&31 puts the 8 column-groups on 8 distinct bank-quads (broadcast
// within each). x reads use the same rotated column so pairing is exact.
// Grid 1024x256 = 4 blocks/CU, 16 waves/CU.

#define DD  1024
#define KK  5
#define CC  3
#define QS  8                  // column-split: threads per row
#define RPB 32                 // rows per block (256 / QS)
#define F4R (DD / 4)           // 256 float4 per row
#define F4T (F4R / QS)         // 32 float4 per thread

__global__ __launch_bounds__(256, 4) void cbc_kernel(
    const float* __restrict__ x,
    const float* __restrict__ comps,
    const float* __restrict__ reas,
    float* __restrict__ out,
    int B)
{
    __shared__ float4 cl[KK * F4R];   // 20480 B

    const int tid = threadIdx.x;
    const int q   = tid & (QS - 1);   // column-group 0..7
    const int r   = tid >> 3;         // row-in-block 0..31
    const int row = blockIdx.x * RPB + r;

    // ---- stage components into LDS (coalesced float4; 5 iters/thread) ----
    const float4* c4 = (const float4*)comps;
    for (int i = tid; i < KK * F4R; i += blockDim.x) cl[i] = c4[i];

    // ---- per-lane reasoning params for class c = q (lanes q>=3 dummy) ----
    // pk = A; nk = (1-A)*B; w = pk-nk; bias = sum nk; invden = 1/sum(pk+nk)
    const int c = (q < CC) ? q : 0;
    float wv[KK], bias = 0.f, den = 0.f;
#pragma unroll
    for (int k = 0; k < KK; ++k) {
        float a = reas[k * (CC * 2) + c * 2 + 0];
        float b = reas[k * (CC * 2) + c * 2 + 1];
        a = fminf(fmaxf(a, 0.f), 1.f);
        b = fminf(fmaxf(b, 0.f), 1.f);
        float nk = (1.f - a) * b;
        wv[k] = a - nk;
        bias += nk;
        den  += a + nk;
    }
    const float invden = 1.f / den;

    __syncthreads();

    if (row < B) {
        // this thread's 32-float4 slice of its row
        const float4* xp = (const float4*)x + (size_t)row * F4R + q * F4T;
        const int     cb = q * F4T;   // comp slice base (f4 index within a k-row)

        float acc[KK];
#pragma unroll
        for (int k = 0; k < KK; ++k) acc[k] = 0.f;

        // continuous stream: no phases, no cross-lane ops, loads always in flight
#pragma unroll 8
        for (int i = 0; i < F4T; ++i) {
            const int ri = (i + q) & (F4T - 1);   // rotation: LDS conflict-free,
            float4 xv = xp[ri];                   // x paired at the same column
#pragma unroll
            for (int k = 0; k < KK; ++k) {
                float4 cv = cl[k * F4R + cb + ri];
                float dx = xv.x - cv.x;
                float dy = xv.y - cv.y;
                float dz = xv.z - cv.z;
                float dw = xv.w - cv.w;
                acc[k] += dx * dx;
                acc[k] += dy * dy;
                acc[k] += dz * dz;
                acc[k] += dw * dw;
            }
        }

        // ---- 8-lane group reduction: 3 steps, stays within the row's lanes ----
#pragma unroll
        for (int k = 0; k < KK; ++k) {
            acc[k] += __shfl_xor(acc[k], 1, 64);
            acc[k] += __shfl_xor(acc[k], 2, 64);
            acc[k] += __shfl_xor(acc[k], 4, 64);
        }

        // ---- epilogue: lanes q=0..2 write this row's 3 class probs ----
        if (q < CC) {
            float num = bias;
#pragma unroll
            for (int k = 0; k < KK; ++k)
                num += __expf(-0.5f * acc[k]) * wv[k];   // variance = 1
            out[(size_t)row * CC + q] = num * invden;
        }
    }
}

extern "C" void kernel_launch(void* const* d_in, const int* in_sizes, int n_in,
                              void* d_out, int out_size, void* d_ws, size_t ws_size,
                              hipStream_t stream) {
    const float* x = (const float*)d_in[0];
    const float* comps = (const float*)d_in[1];
    const float* reas = (const float*)d_in[2];
    float* out = (float*)d_out;
    const int B = in_sizes[0] / DD;   // 32768 rows

    // one thread per (row, column-octant): 32 rows/block -> 1024 blocks,
    // 4 blocks/CU, 16 waves/CU, zero grid-stride (single pass).
    const int blocks = (B + RPB - 1) / RPB;
    cbc_kernel<<<blocks, 256, 0, stream>>>(x, comps, reas, out, B);
}

// Round 9
// 204.513 us; speedup vs baseline: 1.2926x; 1.2926x over previous
//
#include <hip/hip_runtime.h>

// CBC (classification-by-components) fused kernel, v8 — interleaved-column
// thread-per-row-slice with explicit 8-deep load pipeline.
// x:[B,1024] f32, components:[5,1024] f32, reasonings:[5,3,2] f32 -> probs:[B,3] f32.
//
// v7 post-mortem: contiguous-slice ownership scattered each wave-instruction
// into 64 x 16B chunks at 512B stride -> FETCH_SIZE 404 MB (3.1x ideal) and
// the compiler refused to pipeline (VGPR=24). v8 fixes both:
//  - STRIDE-8 OWNERSHIP: thread q owns f4 columns {q, q+8, ...}. Per
//    instruction each row-octet reads one aligned 128B chunk (a full line);
//    8 rows/wave = 8 full lines -> 100% line utilization.
//  - EXPLICIT PIPELINE: two named 8-deep float4 buffers, fully-unrolled
//    static schedule  L(a,0) L(b,1) | C(a,0) L(a,2) | C(b,1) L(b,3) |
//    C(a,2) | C(b,3)  -- loads stay 8-deep in flight through all compute,
//    no copies, no exec-masked prefetch, all indices compile-time.
//    First 16 loads issue before __syncthreads (hidden under LDS staging).
//  - LDS comps at cl[k*256+8i+q]: the 8 q-phases hit 8 distinct bank-quads
//    (all 32 banks exactly once), broadcast across the 8 rows. Conflict-free.
// Reduction: 3 shuffle steps within the 8-lane row group; lanes q<3 store.

#define DD  1024
#define KK  5
#define CC  3
#define QS  8                  // threads per row
#define RPB 32                 // rows per block (256 / QS)
#define F4R (DD / 4)           // 256 float4 per row
#define F4T (F4R / QS)         // 32 float4 per thread
#define UB  8                  // loads in flight per buffer

__global__ __launch_bounds__(256, 4) void cbc_kernel(
    const float* __restrict__ x,
    const float* __restrict__ comps,
    const float* __restrict__ reas,
    float* __restrict__ out,
    int B)
{
    __shared__ float4 cl[KK * F4R];   // 20480 B

    const int tid = threadIdx.x;
    const int q   = tid & (QS - 1);   // column phase 0..7
    const int r   = tid >> 3;         // row-in-block 0..31
    const int row = blockIdx.x * RPB + r;
    const bool live = row < B;

    // this thread's strided view of its row (f4 index q + 8*i)
    const float4* xp = (const float4*)x + (size_t)(live ? row : 0) * F4R + q;

    float acc[KK];
#pragma unroll
    for (int k = 0; k < KK; ++k) acc[k] = 0.f;

    float4 xa[UB], xb[UB];

#define LOADB(BUF, BI)                                                     \
    _Pragma("unroll")                                                      \
    for (int u = 0; u < UB; ++u) BUF[u] = xp[((BI) * UB + u) * QS];

#define COMPUTEB(BUF, BI)                                                  \
    _Pragma("unroll")                                                      \
    for (int u = 0; u < UB; ++u) {                                         \
        const int col = ((BI) * UB + u) * QS + q;                          \
        _Pragma("unroll")                                                  \
        for (int k = 0; k < KK; ++k) {                                     \
            float4 cv = cl[k * F4R + col];                                 \
            float dx = BUF[u].x - cv.x;                                    \
            float dy = BUF[u].y - cv.y;                                    \
            float dz = BUF[u].z - cv.z;                                    \
            float dw = BUF[u].w - cv.w;                                    \
            acc[k] += dx * dx;                                             \
            acc[k] += dy * dy;                                             \
            acc[k] += dz * dz;                                             \
            acc[k] += dw * dw;                                             \
        }                                                                  \
    }

    // ---- blocks 0,1 issued immediately: hidden under LDS staging + sync ----
    LOADB(xa, 0)
    LOADB(xb, 1)

    // ---- stage components into LDS (coalesced float4; 5 iters/thread) ----
    const float4* c4 = (const float4*)comps;
    for (int i = tid; i < KK * F4R; i += blockDim.x) cl[i] = c4[i];

    // ---- per-lane reasoning params for class c = q (lanes q>=3 dummy) ----
    // pk = A; nk = (1-A)*B; w = pk-nk; bias = sum nk; invden = 1/sum(pk+nk)
    const int c = (q < CC) ? q : 0;
    float wv[KK], bias = 0.f, den = 0.f;
#pragma unroll
    for (int k = 0; k < KK; ++k) {
        float a = reas[k * (CC * 2) + c * 2 + 0];
        float b = reas[k * (CC * 2) + c * 2 + 1];
        a = fminf(fmaxf(a, 0.f), 1.f);
        b = fminf(fmaxf(b, 0.f), 1.f);
        float nk = (1.f - a) * b;
        wv[k] = a - nk;
        bias += nk;
        den  += a + nk;
    }
    const float invden = 1.f / den;

    __syncthreads();

    // ---- static pipeline: consume one block, refill the other ----
    COMPUTEB(xa, 0)
    LOADB  (xa, 2)
    COMPUTEB(xb, 1)
    LOADB  (xb, 3)
    COMPUTEB(xa, 2)
    COMPUTEB(xb, 3)

#undef LOADB
#undef COMPUTEB

    // ---- 8-lane group reduction: 3 steps, stays within the row group ----
#pragma unroll
    for (int k = 0; k < KK; ++k) {
        acc[k] += __shfl_xor(acc[k], 1, 64);
        acc[k] += __shfl_xor(acc[k], 2, 64);
        acc[k] += __shfl_xor(acc[k], 4, 64);
    }

    // ---- epilogue: lanes q=0..2 write this row's 3 class probs ----
    if (live && q < CC) {
        float num = bias;
#pragma unroll
        for (int k = 0; k < KK; ++k)
            num += __expf(-0.5f * acc[k]) * wv[k];   // variance = 1
        out[(size_t)row * CC + q] = num * invden;
    }
}

extern "C" void kernel_launch(void* const* d_in, const int* in_sizes, int n_in,
                              void* d_out, int out_size, void* d_ws, size_t ws_size,
                              hipStream_t stream) {
    const float* x = (const float*)d_in[0];
    const float* comps = (const float*)d_in[1];
    const float* reas = (const float*)d_in[2];
    float* out = (float*)d_out;
    const int B = in_sizes[0] / DD;   // 32768 rows

    // one thread per (row, column-phase): 32 rows/block -> 1024 blocks,
    // single pass, no grid-stride.
    const int blocks = (B + RPB - 1) / RPB;
    cbc_kernel<<<blocks, 256, 0, stream>>>(x, comps, reas, out, B);
}

// Round 10
// 190.418 us; speedup vs baseline: 1.3883x; 1.0740x over previous
//
#include <hip/hip_runtime.h>

// CBC (classification-by-components) fused kernel, v9 = v1 + DPP reduction.
// x:[B,1024] f32, components:[5,1024] f32, reasonings:[5,3,2] f32 -> probs:[B,3] f32.
//
// Ladder: v1 35us / v4 39 / v5 47 / v6 44 / v7 128 / v8 49. Every variant that
// added DS work or restructured phases lost to v1. Residual theory: v1's 30
// __shfl_xor per row are DS-pipe ops (~5.8cyc throughput, 6-deep dependent
// chain, one DS unit shared by 4 SIMDs) -> ~22k cyc/CU serial occupancy plus
// a 300-700cyc per-row tail. v9 keeps v1 byte-identical except the butterfly
// becomes the classic gfx9 wave64 DPP sum (row_shr:1/2/4/8, row_bcast:15,
// row_bcast:31 + readlane 63): VALU-pipe only, ZERO DS ops in the kernel,
// 5 independent chains pipeline -> tail shrinks ~10x.

#define DD 1024
#define KK 5
#define CC 3
#define F4_PER_ROW (DD / 4)            // 256 float4 per row
#define F4_PER_LANE (F4_PER_ROW / 64)  // 4 per lane

// one DPP-shifted add step: v += dpp_move(v); invalid lanes contribute 0
template <int CTRL>
__device__ __forceinline__ float dpp_add(float v) {
    int moved = __builtin_amdgcn_update_dpp(
        0, __float_as_int(v), CTRL, 0xf, 0xf, true);
    return v + __int_as_float(moved);
}

// full 64-lane sum on the VALU pipe; result valid in lane 63
__device__ __forceinline__ float wave_sum_dpp(float v) {
    v = dpp_add<0x111>(v);   // row_shr:1
    v = dpp_add<0x112>(v);   // row_shr:2
    v = dpp_add<0x114>(v);   // row_shr:4
    v = dpp_add<0x118>(v);   // row_shr:8   -> lane15 of each row16 = row sum
    v = dpp_add<0x142>(v);   // row_bcast:15 -> lane31 = sum of lower 32 (per half)
    v = dpp_add<0x143>(v);   // row_bcast:31 -> lane63 = sum of all 64
    return v;
}

__global__ __launch_bounds__(256) void cbc_kernel(
    const float* __restrict__ x,
    const float* __restrict__ comps,
    const float* __restrict__ reas,
    float* __restrict__ out,
    int B)
{
    const int lane = threadIdx.x & 63;
    const int waves_per_block = blockDim.x >> 6;
    const int wave_global = blockIdx.x * waves_per_block + (threadIdx.x >> 6);
    const int n_waves = gridDim.x * waves_per_block;

    // --- component fragments into registers: lane i owns float4 columns j*64+i ---
    float4 cf[KK][F4_PER_LANE];
    const float4* comps4 = (const float4*)comps;
#pragma unroll
    for (int k = 0; k < KK; ++k)
#pragma unroll
        for (int j = 0; j < F4_PER_LANE; ++j)
            cf[k][j] = comps4[k * F4_PER_ROW + j * 64 + lane];

    // --- reasoning weights (uniform scalar loads, cached; tiny) ---
    // pk = A; nk = (1-A)*B; w = pk-nk; bias = sum_k nk; invden = 1/sum_k(pk+nk)
    float w[CC][KK], bias[CC], invden[CC];
#pragma unroll
    for (int c = 0; c < CC; ++c) {
        float nsum = 0.f, dsum = 0.f;
#pragma unroll
        for (int k = 0; k < KK; ++k) {
            float a = reas[k * (CC * 2) + c * 2 + 0];
            float b = reas[k * (CC * 2) + c * 2 + 1];
            a = fminf(fmaxf(a, 0.f), 1.f);
            b = fminf(fmaxf(b, 0.f), 1.f);
            float nk = (1.f - a) * b;
            w[c][k] = a - nk;
            nsum += nk;
            dsum += a + nk;
        }
        bias[c] = nsum;
        invden[c] = 1.f / dsum;
    }

    const float4* x4 = (const float4*)x;

    for (int row = wave_global; row < B; row += n_waves) {
        float acc[KK];
#pragma unroll
        for (int k = 0; k < KK; ++k) acc[k] = 0.f;

#pragma unroll
        for (int j = 0; j < F4_PER_LANE; ++j) {
            float4 xv = x4[(size_t)row * F4_PER_ROW + j * 64 + lane];
#pragma unroll
            for (int k = 0; k < KK; ++k) {
                float dx = xv.x - cf[k][j].x;
                float dy = xv.y - cf[k][j].y;
                float dz = xv.z - cf[k][j].z;
                float dw = xv.w - cf[k][j].w;
                acc[k] += dx * dx;
                acc[k] += dy * dy;
                acc[k] += dz * dz;
                acc[k] += dw * dw;
            }
        }

        // --- wave64 sum per k on the VALU pipe (no DS ops); broadcast via
        //     readlane 63 -> SGPR, uniform across the wave ---
        float d2[KK];
#pragma unroll
        for (int k = 0; k < KK; ++k) {
            float s = wave_sum_dpp(acc[k]);
            d2[k] = __int_as_float(
                __builtin_amdgcn_readlane(__float_as_int(s), 63));
        }

        if (lane < CC) {
            const int c = lane;
            float num = bias[c];
#pragma unroll
            for (int k = 0; k < KK; ++k)
                num += __expf(-0.5f * d2[k]) * w[c][k];   // variance = 1
            out[(size_t)row * CC + c] = num * invden[c];
        }
    }
}

extern "C" void kernel_launch(void* const* d_in, const int* in_sizes, int n_in,
                              void* d_out, int out_size, void* d_ws, size_t ws_size,
                              hipStream_t stream) {
    const float* x = (const float*)d_in[0];
    const float* comps = (const float*)d_in[1];
    const float* reas = (const float*)d_in[2];
    float* out = (float*)d_out;
    const int B = in_sizes[0] / DD;   // 32768

    // identical launch shape to v1: 1024 blocks x 256 threads = 4096 waves,
    // 8 rows per wave grid-stride.
    const int blocks = 1024;
    cbc_kernel<<<blocks, 256, 0, stream>>>(x, comps, reas, out, B);
}